// Round 3
// baseline (3866.881 us; speedup 1.0000x reference)
//
#include <hip/hip_runtime.h>

// Conv2d: input (64,8,256,256) f32, filter (8,8,3,3) OIHW, VALID, stride 1.
// out (64,8,254,254) f32.
//
// Round-3 structure:
//  - Direct global loads (no input LDS; reuse via L1/L2, input fits in L3).
//  - Round-1's PROVEN-clean store geometry: block = 64x16 output tile,
//    wave = 4 rows x 16 lane-groups of 4 px (round-2's full-row-per-wave
//    float2 stores amplified WRITE_SIZE 3.6x).
//  - Explicit XCD swizzle: XCD k owns all tiles of images n = k mod 8, so
//    x/y halo re-reads are same-XCD L2 hits.
//  - c-loop fully unrolled -> 48 independent global loads hoistable for
//    latency hiding; VGPR capped at 128 (4 waves/EU).
//  - Filter packed in LDS [c][r][m][s]: 6 broadcast ds_read_b128 per (c,r).

__global__ __launch_bounds__(256, 4)
void conv2d_direct2_kernel(const float* __restrict__ inp,
                           const float* __restrict__ filt,
                           float* __restrict__ out) {
    __shared__ float s_f[576];   // [c][r][m][s] : ((c*3+r)*8+m)*3+s

    const int tid = threadIdx.x;
    for (int i = tid; i < 576; i += 256) {
        int m = i / 72;
        int c = (i / 9) % 8;
        int r = (i / 3) % 3;
        int s = i % 3;
        s_f[((c * 3 + r) * 8 + m) * 3 + s] = filt[i];
    }
    __syncthreads();

    // XCD-aware decode: blocks on XCD k (= bid%8) cover ALL tiles of images
    // n = k, k+8, ... so halo-overlapping neighbors share that XCD's L2.
    const int bid = blockIdx.x;
    const int xcd = bid & 7;
    const int loc = bid >> 3;          // 0..511
    const int tx  = loc & 3;           // 4 x-tiles of 64
    const int ty  = (loc >> 2) & 15;   // 16 y-tiles of 16
    const int n   = xcd + 8 * (loc >> 6);

    const int xg = tid & 15;           // 16 x-groups of 4 px
    const int py = tid >> 4;           // 16 rows (wave = 4 rows x 16 groups)
    const int x0 = tx * 64 + xg * 4;   // 0..252
    const int y  = ty * 16 + py;       // 0..255

    if (y >= 254) return;              // after the single barrier

    const float* in_n = inp + (size_t)n * (8 * 256 * 256);

    float acc[8][4];
    #pragma unroll
    for (int m = 0; m < 8; ++m)
        #pragma unroll
        for (int i = 0; i < 4; ++i) acc[m][i] = 0.0f;

    // tail lane (x0=252): read iv[4],iv[5] from x=254,255 instead of OOB
    // 256,257; they only feed px>=254 accs which are never stored.
    const int o2 = (x0 <= 250) ? 4 : 2;

    #pragma unroll
    for (int c = 0; c < 8; ++c) {
        const float* ip = in_n + ((c * 256 + y) * 256 + x0);
        #pragma unroll
        for (int r = 0; r < 3; ++r) {
            float iv[6];
            const float4 v0 = *(const float4*)(ip + r * 256);       // 16B aligned
            iv[0] = v0.x; iv[1] = v0.y; iv[2] = v0.z; iv[3] = v0.w;
            const float2 v1 = *(const float2*)(ip + r * 256 + o2);  // 8B aligned
            iv[4] = v1.x; iv[5] = v1.y;

            float fr[24];
            const float* fp = &s_f[(c * 3 + r) * 24];
            #pragma unroll
            for (int j = 0; j < 24; ++j) fr[j] = fp[j];             // 6x broadcast b128

            #pragma unroll
            for (int s = 0; s < 3; ++s) {
                #pragma unroll
                for (int m = 0; m < 8; ++m) {
                    const float fv = fr[m * 3 + s];
                    #pragma unroll
                    for (int i = 0; i < 4; ++i)
                        acc[m][i] = fmaf(iv[i + s], fv, acc[m][i]);
                }
            }
        }
    }

    const bool full = (x0 + 4 <= 254);   // only x0==252 is partial
    #pragma unroll
    for (int m = 0; m < 8; ++m) {
        float* op = out + ((((size_t)n * 8 + m) * 254 + y) * 254 + x0);
        float2 lo; lo.x = acc[m][0]; lo.y = acc[m][1];
        *(float2*)op = lo;                                  // 8B aligned
        if (full) {
            float2 hi; hi.x = acc[m][2]; hi.y = acc[m][3];
            *(float2*)(op + 2) = hi;
        }
    }
}

extern "C" void kernel_launch(void* const* d_in, const int* in_sizes, int n_in,
                              void* d_out, int out_size, void* d_ws, size_t ws_size,
                              hipStream_t stream) {
    const float* inp  = (const float*)d_in[0];   // (64,8,256,256)
    const float* filt = (const float*)d_in[1];   // (8,8,3,3)
    float* outp = (float*)d_out;                 // (64,8,254,254)

    dim3 grid(4096);   // 4 tx * 16 ty * 64 n, XCD-swizzled in-kernel
    dim3 block(256);
    conv2d_direct2_kernel<<<grid, block, 0, stream>>>(inp, filt, outp);
}